// Round 1
// baseline (160.551 us; speedup 1.0000x reference)
//
#include <hip/hip_runtime.h>

// ---------------------------------------------------------------------------
// MultiHeadAttentionEncoder: x=[last batch][2048,1024] -> per-head (hd=64)
// QKV proj (bf16, fp32-acc MFMA) -> flash attention -> out [1,2048,1024] fp32.
//
// ws layout: qb[16][2048][64] bf16 (q pre-scaled by 0.125*log2e),
//            kb[16][2048][64] bf16, vT[16][64][2048] bf16  (12 MB total)
// ---------------------------------------------------------------------------

#define NUM_HEADS 16
#define HEAD_DIM  64
#define SEQ       2048
#define DIM       1024
#define BATCH     4

typedef unsigned short u16;
typedef unsigned int   u32;
typedef __bf16 bf16x8 __attribute__((ext_vector_type(8)));
typedef float  f32x4  __attribute__((ext_vector_type(4)));

// 1/sqrt(64) * log2(e): softmax computed in exp2 domain (v_exp_f32 is 2^x)
#define QSCALE (0.125f * 1.44269504088896340736f)

__device__ __forceinline__ u16 f2bf(float f) {            // RNE float->bf16
  u32 u = __builtin_bit_cast(u32, f);
  u += 0x7FFFu + ((u >> 16) & 1u);
  return (u16)(u >> 16);
}

__device__ __forceinline__ bf16x8 as_frag(uint4 v) {
  return __builtin_bit_cast(bf16x8, v);
}

__device__ __forceinline__ f32x4 mfma16(bf16x8 a, bf16x8 b, f32x4 c) {
  return __builtin_amdgcn_mfma_f32_16x16x32_bf16(a, b, c, 0, 0, 0);
}

__device__ __forceinline__ void gload16(const void* g, void* l) {
  __builtin_amdgcn_global_load_lds(
      (const __attribute__((address_space(1))) void*)g,
      (__attribute__((address_space(3))) void*)l, 16, 0, 0);
}

// ---------------------------------------------------------------------------
// Projection kernel: grid 256 = 16 heads x 16 s-tiles(128 rows), 256 threads.
// Frag conventions (m89-verified): A lane l: A[l&15][(l>>4)*8+j];
// B lane l: B[(l>>4)*8+j][l&15]; D lane l: D[(l>>4)*4+r][l&15].
// LDS tiles XOR-swizzled at 16B units: unit(row,slot) holds cols (slot^(row&7))*8..+8
// ---------------------------------------------------------------------------
__global__ __launch_bounds__(256) void proj_kernel(
    const float* __restrict__ x,    // [SEQ][DIM], already offset to last batch
    const float* __restrict__ Wq, const float* __restrict__ bq,
    const float* __restrict__ Wk, const float* __restrict__ bk,
    const float* __restrict__ Wv, const float* __restrict__ bv,
    u16* __restrict__ qb, u16* __restrict__ kb, u16* __restrict__ vT)
{
  const int bid = blockIdx.x;
  const int h   = bid & 15;          // h = bid%16 -> same head stays on one XCD
  const int st0 = (bid >> 4) * 128;
  const int tid  = threadIdx.x;
  const int w    = tid >> 6;
  const int lane = tid & 63;
  const int g    = lane >> 4;
  const int c    = lane & 15;

  __shared__ __align__(16) u16 xl[128 * 64];      // 16 KB
  __shared__ __align__(16) u16 wl[3][64 * 64];    // 24 KB

  // ---- stage x tile (128x64 fp32 -> bf16, swizzled) ----
#pragma unroll
  for (int it = 0; it < 8; ++it) {
    int idx  = tid + it * 256;                    // float4 unit, 2048 total
    int row  = idx >> 4;
    int col4 = idx & 15;
    float4 f = *(const float4*)(x + (size_t)(st0 + row) * DIM + h * HEAD_DIM + col4 * 4);
    ushort4 b;
    b.x = f2bf(f.x); b.y = f2bf(f.y); b.z = f2bf(f.z); b.w = f2bf(f.w);
    int byte = row * 128 + (((col4 >> 1) ^ (row & 7)) << 4) + (col4 & 1) * 8;
    *(ushort4*)((char*)xl + byte) = b;
  }
  // ---- stage Wq/Wk/Wv (each 64x64 fp32 -> bf16, swizzled) ----
  const float* const Ws[3] = {Wq + (size_t)h * 4096, Wk + (size_t)h * 4096, Wv + (size_t)h * 4096};
#pragma unroll
  for (int it = 0; it < 12; ++it) {
    const int mat = it >> 2;                      // compile-time after unroll
    int rem  = tid + (it & 3) * 256;              // 0..1023 float4 units
    int row  = rem >> 4;
    int col4 = rem & 15;
    float4 f = *(const float4*)(Ws[mat] + row * HEAD_DIM + col4 * 4);
    ushort4 b;
    b.x = f2bf(f.x); b.y = f2bf(f.y); b.z = f2bf(f.z); b.w = f2bf(f.w);
    int byte = row * 128 + (((col4 >> 1) ^ (row & 7)) << 4) + (col4 & 1) * 8;
    *(ushort4*)((char*)wl[mat] + byte) = b;
  }
  __syncthreads();

  // ---- x A-frags: rows w*32 + rt*16 + c, k = ch*32 + g*8 + j ----
  bf16x8 xa[2][2];
#pragma unroll
  for (int rt = 0; rt < 2; ++rt)
#pragma unroll
    for (int ch = 0; ch < 2; ++ch) {
      int rl = w * 32 + rt * 16 + c;
      int byte = rl * 128 + ((((ch << 2) + g) ^ (c & 7)) << 4);
      xa[rt][ch] = as_frag(*(const uint4*)((const char*)xl + byte));
    }

  // ---- q, k:  D[s][e] = x @ W^T;  q additionally (..+b)*QSCALE ----
#pragma unroll
  for (int mat = 0; mat < 2; ++mat) {
    const float* bias = (mat == 0) ? bq : bk;
    u16* dst = (mat == 0) ? qb : kb;
#pragma unroll
    for (int eb = 0; eb < 4; ++eb) {
      bf16x8 wb[2];
#pragma unroll
      for (int ch = 0; ch < 2; ++ch) {
        int e = eb * 16 + c;
        int byte = e * 128 + ((((ch << 2) + g) ^ (c & 7)) << 4);
        wb[ch] = as_frag(*(const uint4*)((const char*)wl[mat] + byte));
      }
      float bval = bias[h * HEAD_DIM + eb * 16 + c];
#pragma unroll
      for (int rt = 0; rt < 2; ++rt) {
        f32x4 acc = {0.f, 0.f, 0.f, 0.f};
        acc = mfma16(xa[rt][0], wb[0], acc);
        acc = mfma16(xa[rt][1], wb[1], acc);
#pragma unroll
        for (int i = 0; i < 4; ++i) {
          float v = acc[i] + bval;
          if (mat == 0) v *= QSCALE;
          int srow = st0 + w * 32 + rt * 16 + g * 4 + i;
          dst[((size_t)h * SEQ + srow) * HEAD_DIM + eb * 16 + c] = f2bf(v);
        }
      }
    }
  }

  // ---- v, stored transposed: D[e][s] = Wv @ x^T  (x frags reused as B) ----
#pragma unroll
  for (int eb = 0; eb < 4; ++eb) {
    bf16x8 wa[2];
#pragma unroll
    for (int ch = 0; ch < 2; ++ch) {
      int e = eb * 16 + c;
      int byte = e * 128 + ((((ch << 2) + g) ^ (c & 7)) << 4);
      wa[ch] = as_frag(*(const uint4*)((const char*)wl[2] + byte));
    }
    float bvv[4];
#pragma unroll
    for (int i = 0; i < 4; ++i) bvv[i] = bv[h * HEAD_DIM + eb * 16 + g * 4 + i];
#pragma unroll
    for (int rt = 0; rt < 2; ++rt) {
      f32x4 acc = {0.f, 0.f, 0.f, 0.f};
      acc = mfma16(wa[0], xa[rt][0], acc);
      acc = mfma16(wa[1], xa[rt][1], acc);
#pragma unroll
      for (int i = 0; i < 4; ++i) {
        int e = eb * 16 + g * 4 + i;
        vT[((size_t)h * HEAD_DIM + e) * SEQ + st0 + w * 32 + rt * 16 + c] =
            f2bf(acc[i] + bvv[i]);
      }
    }
  }
}

// ---------------------------------------------------------------------------
// Flash attention: grid 256 = 16 heads x 16 q-tiles(128), 256 threads (4 waves
// x 32 q-rows). K/V tiles of 64 double-buffered in LDS via global_load_lds
// (linear dest + inverse-swizzled global source). Swapped QK^T (mfma(K,Q)) so
// each lane's D-regs hold P^T values that feed PV B-frags with ZERO shuffles
// via a K-index permutation shared by the V A-frags (2x ds_read_b64 each).
// ---------------------------------------------------------------------------
__global__ __launch_bounds__(256) void attn_kernel(
    const u16* __restrict__ qb, const u16* __restrict__ kb,
    const u16* __restrict__ vT, float* __restrict__ out)
{
  const int bid = blockIdx.x;
  const int h   = bid & 15;
  const int s0  = (bid >> 4) * 128;
  const int tid  = threadIdx.x;
  const int w    = tid >> 6;
  const int lane = tid & 63;
  const int g    = lane >> 4;
  const int c    = lane & 15;
  const int sw   = s0 + w * 32;

  __shared__ __align__(16) char kbuf[2][8192];   // [64 t][64 d] bf16, swizzled
  __shared__ __align__(16) char vbuf[2][8192];   // [64 e][64 t] bf16, swizzled

  const u16* kbh = kb + (size_t)h * SEQ * HEAD_DIM;
  const u16* vth = vT + (size_t)h * HEAD_DIM * SEQ;

  // hoist Q B-frags (rows sw+rt*16+c, k = ch*32+g*8..+8); q already scaled
  bf16x8 qf[2][2];
#pragma unroll
  for (int rt = 0; rt < 2; ++rt)
#pragma unroll
    for (int ch = 0; ch < 2; ++ch)
      qf[rt][ch] = as_frag(*(const uint4*)(
          qb + ((size_t)h * SEQ + sw + rt * 16 + c) * HEAD_DIM + ch * 32 + g * 8));

  f32x4 acc[2][4] = {};                // out^T: lane holds e=eb*16+g*4+r, s=c
  float m_[2] = {-3e38f, -3e38f};
  float l_[2] = {0.f, 0.f};

  // stage one K tile + one V tile (8KB each) into buf; 512 16B units each,
  // unit u=(row,slot): source cols (slot^(row&7))*8..+8  (inverse of read swz)
  auto stage = [&](int buf, int t0) {
#pragma unroll
    for (int q2 = 0; q2 < 2; ++q2) {
      int u  = (w * 2 + q2) * 64 + lane;
      int rr = u >> 3;
      int sl = u & 7;
      const char* gk = (const char*)(kbh + (size_t)(t0 + rr) * HEAD_DIM) +
                       ((sl ^ (rr & 7)) << 4);
      gload16(gk, &kbuf[buf][(w * 2 + q2) * 1024]);
      const char* gv = (const char*)(vth + (size_t)rr * SEQ + t0) +
                       ((sl ^ (rr & 7)) << 4);
      gload16(gv, &vbuf[buf][(w * 2 + q2) * 1024]);
    }
  };

  stage(0, 0);
  __syncthreads();                      // implicit vmcnt(0) drains the loads

  int cur = 0;
  for (int t = 0; t < SEQ / 64; ++t) {
    if (t < SEQ / 64 - 1) stage(cur ^ 1, (t + 1) * 64);   // overlap w/ compute

    // ---- QK^T (swapped): ST[t_loc][s] = sum_d kb[t][d] * qb_scaled[s][d] ----
    f32x4 st_[2][4];
#pragma unroll
    for (int tb = 0; tb < 4; ++tb) {
      bf16x8 ka0, ka1;
      {
        int rr = tb * 16 + c;
        int b0 = rr * 128 + (((0 + g) ^ (c & 7)) << 4);
        int b1 = rr * 128 + (((4 + g) ^ (c & 7)) << 4);
        ka0 = as_frag(*(const uint4*)(kbuf[cur] + b0));
        ka1 = as_frag(*(const uint4*)(kbuf[cur] + b1));
      }
#pragma unroll
      for (int rt = 0; rt < 2; ++rt) {
        f32x4 z = {0.f, 0.f, 0.f, 0.f};
        z = mfma16(ka0, qf[rt][0], z);
        st_[rt][tb] = mfma16(ka1, qf[rt][1], z);
      }
    }

    // ---- online softmax (exp2 domain); lane's 16 vals all belong to s=c ----
    u32 pk[2][8];
#pragma unroll
    for (int rt = 0; rt < 2; ++rt) {
      float mt = -3e38f;
#pragma unroll
      for (int tb = 0; tb < 4; ++tb)
#pragma unroll
        for (int i = 0; i < 4; ++i) mt = fmaxf(mt, st_[rt][tb][i]);
      mt = fmaxf(mt, __shfl_xor(mt, 16));
      mt = fmaxf(mt, __shfl_xor(mt, 32));
      float mn = fmaxf(m_[rt], mt);
      float al = exp2f(m_[rt] - mn);    // m_ init -3e38: exp2(-inf-ish)=0, no NaN
      float p[4][4];
      float rs = 0.f;
#pragma unroll
      for (int tb = 0; tb < 4; ++tb)
#pragma unroll
        for (int i = 0; i < 4; ++i) {
          p[tb][i] = exp2f(st_[rt][tb][i] - mn);
          rs += p[tb][i];
        }
      rs += __shfl_xor(rs, 16);
      rs += __shfl_xor(rs, 32);
      l_[rt] = l_[rt] * al + rs;
      m_[rt] = mn;
#pragma unroll
      for (int eb = 0; eb < 4; ++eb) acc[rt][eb] *= al;
#pragma unroll
      for (int tb = 0; tb < 4; ++tb) {
        pk[rt][tb * 2 + 0] = (u32)f2bf(p[tb][0]) | ((u32)f2bf(p[tb][1]) << 16);
        pk[rt][tb * 2 + 1] = (u32)f2bf(p[tb][2]) | ((u32)f2bf(p[tb][3]) << 16);
      }
    }

    // ---- PV: out^T += V^T @ P^T with K-permutation pi(g*8+j) =
    //      (2k0+(j>>2))*16 + g*4 + (j&3): B-frag = lane's own pk, zero shfl ----
#pragma unroll
    for (int eb = 0; eb < 4; ++eb) {
      int e = eb * 16 + c;
#pragma unroll
      for (int k0 = 0; k0 < 2; ++k0) {
        int b0 = e * 128 + ((((k0 << 2) + 0 + (g >> 1)) ^ (c & 7)) << 4) + (g & 1) * 8;
        int b1 = e * 128 + ((((k0 << 2) + 2 + (g >> 1)) ^ (c & 7)) << 4) + (g & 1) * 8;
        uint2 lo = *(const uint2*)(vbuf[cur] + b0);
        uint2 hi = *(const uint2*)(vbuf[cur] + b1);
        bf16x8 va = as_frag(make_uint4(lo.x, lo.y, hi.x, hi.y));
#pragma unroll
        for (int rt = 0; rt < 2; ++rt) {
          bf16x8 pf = as_frag(make_uint4(pk[rt][k0 * 4 + 0], pk[rt][k0 * 4 + 1],
                                         pk[rt][k0 * 4 + 2], pk[rt][k0 * 4 + 3]));
          acc[rt][eb] = mfma16(va, pf, acc[rt][eb]);
        }
      }
    }

    __syncthreads();    // drains next-tile loads (vmcnt0) + protects cur buf
    cur ^= 1;
  }

  // ---- epilogue: out[s][h*64+e] = acc/l ----
#pragma unroll
  for (int rt = 0; rt < 2; ++rt) {
    float rinv = 1.0f / l_[rt];
#pragma unroll
    for (int eb = 0; eb < 4; ++eb) {
      float4 o;
      o.x = acc[rt][eb][0] * rinv;
      o.y = acc[rt][eb][1] * rinv;
      o.z = acc[rt][eb][2] * rinv;
      o.w = acc[rt][eb][3] * rinv;
      *(float4*)(out + (size_t)(sw + rt * 16 + c) * DIM + h * HEAD_DIM +
                 eb * 16 + g * 4) = o;
    }
  }
}

extern "C" void kernel_launch(void* const* d_in, const int* in_sizes, int n_in,
                              void* d_out, int out_size, void* d_ws, size_t ws_size,
                              hipStream_t stream) {
  const float* le = (const float*)d_in[0];
  const float* x  = le + (size_t)(BATCH - 1) * SEQ * DIM;   // last image only
  const float* Wq = (const float*)d_in[1];
  const float* bq = (const float*)d_in[2];
  const float* Wk = (const float*)d_in[3];
  const float* bk = (const float*)d_in[4];
  const float* Wv = (const float*)d_in[5];
  const float* bv = (const float*)d_in[6];

  u16* qb = (u16*)d_ws;                                   // 4 MB
  u16* kb = qb + (size_t)NUM_HEADS * SEQ * HEAD_DIM;      // 4 MB
  u16* vT = kb + (size_t)NUM_HEADS * SEQ * HEAD_DIM;      // 4 MB

  proj_kernel<<<256, 256, 0, stream>>>(x, Wq, bq, Wk, bk, Wv, bv, qb, kb, vT);
  attn_kernel<<<256, 256, 0, stream>>>(qb, kb, vT, (float*)d_out);
}

// Round 10
// 136.850 us; speedup vs baseline: 1.1732x; 1.1732x over previous
//
#include <hip/hip_runtime.h>

// ---------------------------------------------------------------------------
// MultiHeadAttentionEncoder: x = last batch [2048,1024] fp32.
// R9: R1's PROVEN numeric path verbatim (libm exp2f, __shfl_xor 16/32, manual
// RNE f2bf, fp32 rs in R1's order, always-rescale, NO KV-split, NO permlane,
// NO builtin-exp2) + two provably bit-neutral changes:
//   (a) fast proj (operand-swapped MFMA = bit-commutative; same RNE),
//   (b) attn 64-row q-tiles (4 waves x 16 rows, grid 512) - per-row math is
//       wave-assignment-independent (reductions only combine same-s lanes).
// ws: qb[16][2048][64] bf16 (q pre-scaled 0.125*log2e) | kb same |
//     vT[16][64][2048] bf16   (12 MB)
// ---------------------------------------------------------------------------

#define NH  16
#define HD  64
#define SEQ 2048
#define DIM 1024

typedef unsigned short u16;
typedef unsigned int   u32;
typedef __bf16 bf16x8 __attribute__((ext_vector_type(8)));
typedef float  f32x4  __attribute__((ext_vector_type(4)));

#define QSCALE (0.125f * 1.44269504088896340736f)  // 1/sqrt(64) * log2(e)

__device__ __forceinline__ u16 f2bf(float f) {            // RNE float->bf16
  u32 u = __builtin_bit_cast(u32, f);
  u += 0x7FFFu + ((u >> 16) & 1u);
  return (u16)(u >> 16);
}
__device__ __forceinline__ u32 pkbf(float a, float b) {   // manual RNE pack
  return (u32)f2bf(a) | ((u32)f2bf(b) << 16);
}
__device__ __forceinline__ bf16x8 as_frag(uint4 v) { return __builtin_bit_cast(bf16x8, v); }
__device__ __forceinline__ f32x4 mfma16(bf16x8 a, bf16x8 b, f32x4 c) {
  return __builtin_amdgcn_mfma_f32_16x16x32_bf16(a, b, c, 0, 0, 0);
}
__device__ __forceinline__ void gload16(const void* g, void* l) {
  __builtin_amdgcn_global_load_lds(
      (const __attribute__((address_space(1))) void*)g,
      (__attribute__((address_space(3))) void*)l, 16, 0, 0);
}

// ---------------------------------------------------------------------------
// proj: grid 512 = 16 heads x 32 s-tiles(64 rows), 256 thr (4 waves x 16 rows).
// Bit-identical outputs to R1's proj (same products, same K-order, same RNE).
// LDS 16B-unit XOR swizzle: unit(row,slot) holds cols (slot^(row&7))*8..+8.
// ---------------------------------------------------------------------------
__global__ __launch_bounds__(256) void proj_kernel(
    const float* __restrict__ x,
    const float* __restrict__ Wq, const float* __restrict__ bq,
    const float* __restrict__ Wk, const float* __restrict__ bk,
    const float* __restrict__ Wv, const float* __restrict__ bv,
    u16* __restrict__ qb, u16* __restrict__ kb, u16* __restrict__ vT)
{
  const int bid = blockIdx.x;
  const int h   = bid & 15;
  const int st0 = (bid >> 4) * 64;
  const int tid  = threadIdx.x;
  const int w    = tid >> 6;
  const int lane = tid & 63;
  const int g    = lane >> 4;
  const int c    = lane & 15;

  __shared__ __align__(16) u16 xl[64 * 64];       // 8 KB
  __shared__ __align__(16) u16 wl[3][64 * 64];    // 24 KB

  // stage x tile (64x64 f32 -> bf16 RNE, swizzled): 1024 float4 units
#pragma unroll
  for (int it = 0; it < 4; ++it) {
    int u    = tid + it * 256;
    int row  = u >> 4;
    int col4 = u & 15;
    float4 f = *(const float4*)(x + (size_t)(st0 + row) * DIM + h * HD + col4 * 4);
    int byte = row * 128 + (((col4 >> 1) ^ (row & 7)) << 4) + (col4 & 1) * 8;
    uint2 pkd;
    pkd.x = pkbf(f.x, f.y);
    pkd.y = pkbf(f.z, f.w);
    *(uint2*)((char*)xl + byte) = pkd;
  }
  // stage Wq/Wk/Wv (64x64 f32 each)
  const float* const Ws[3] = {Wq + (size_t)h * 4096, Wk + (size_t)h * 4096,
                              Wv + (size_t)h * 4096};
#pragma unroll
  for (int it = 0; it < 12; ++it) {
    const int mat = it >> 2;
    int u    = tid + (it & 3) * 256;
    int row  = u >> 4;
    int col4 = u & 15;
    float4 f = *(const float4*)(Ws[mat] + row * HD + col4 * 4);
    int byte = row * 128 + (((col4 >> 1) ^ (row & 7)) << 4) + (col4 & 1) * 8;
    uint2 pkd;
    pkd.x = pkbf(f.x, f.y);
    pkd.y = pkbf(f.z, f.w);
    *(uint2*)((char*)wl[mat] + byte) = pkd;
  }
  __syncthreads();

  // x frags for this wave's 16 rows (serve as both A and B operand)
  bf16x8 xa[2];
#pragma unroll
  for (int ch = 0; ch < 2; ++ch) {
    int byte = (w * 16 + c) * 128 + ((((ch << 2) + g) ^ (c & 7)) << 4);
    xa[ch] = as_frag(*(const uint4*)((const char*)xl + byte));
  }
  const int sbase = st0 + w * 16;

  // q, k: D = W @ x^T -> lane (g,c): e = eb*16+g*4+i, s = sbase+c
#pragma unroll
  for (int mat = 0; mat < 2; ++mat) {
    const float* bias = (mat == 0) ? bq : bk;
    u16* dst = (mat == 0) ? qb : kb;
#pragma unroll
    for (int eb = 0; eb < 4; ++eb) {
      bf16x8 wf0, wf1;
      {
        int b0 = (eb * 16 + c) * 128 + (((0 + g) ^ (c & 7)) << 4);
        int b1 = (eb * 16 + c) * 128 + (((4 + g) ^ (c & 7)) << 4);
        wf0 = as_frag(*(const uint4*)((const char*)wl[mat] + b0));
        wf1 = as_frag(*(const uint4*)((const char*)wl[mat] + b1));
      }
      float4 b4 = *(const float4*)(bias + h * HD + eb * 16 + g * 4);
      f32x4 acc = {0.f, 0.f, 0.f, 0.f};
      acc = mfma16(wf0, xa[0], acc);
      acc = mfma16(wf1, xa[1], acc);
      float v0 = acc[0] + b4.x, v1 = acc[1] + b4.y;
      float v2 = acc[2] + b4.z, v3 = acc[3] + b4.w;
      if (mat == 0) { v0 *= QSCALE; v1 *= QSCALE; v2 *= QSCALE; v3 *= QSCALE; }
      uint2 st;
      st.x = pkbf(v0, v1);
      st.y = pkbf(v2, v3);
      *(uint2*)(dst + ((size_t)h * SEQ + sbase + c) * HD + eb * 16 + g * 4) = st;
    }
  }

  // v: D = x @ Wv^T -> lane (g,c): s = sbase+g*4+i, e = eb*16+c -> vT[e][s]
#pragma unroll
  for (int eb = 0; eb < 4; ++eb) {
    bf16x8 wf0, wf1;
    {
      int b0 = (eb * 16 + c) * 128 + (((0 + g) ^ (c & 7)) << 4);
      int b1 = (eb * 16 + c) * 128 + (((4 + g) ^ (c & 7)) << 4);
      wf0 = as_frag(*(const uint4*)((const char*)wl[2] + b0));
      wf1 = as_frag(*(const uint4*)((const char*)wl[2] + b1));
    }
    float bvv = bv[h * HD + eb * 16 + c];
    f32x4 acc = {0.f, 0.f, 0.f, 0.f};
    acc = mfma16(xa[0], wf0, acc);
    acc = mfma16(xa[1], wf1, acc);
    uint2 st;
    st.x = pkbf(acc[0] + bvv, acc[1] + bvv);
    st.y = pkbf(acc[2] + bvv, acc[3] + bvv);
    *(uint2*)(vT + ((size_t)h * HD + eb * 16 + c) * SEQ + sbase + g * 4) = st;
  }
}

// ---------------------------------------------------------------------------
// attn: grid 512 = 16h x 32 q-tiles(64 rows). 256 thr = 4 waves x 16 q-rows.
// Full 32 KV-tiles per block (NO split). R1's numeric ops verbatim:
// exp2f (libm), __shfl_xor 16/32, fp32 rs in R1's order, f2bf RNE packing,
// always-rescale (p_max = 1 exact). KVBLK=64 double-buffered global_load_lds.
// ---------------------------------------------------------------------------
__global__ __launch_bounds__(256, 2) void attn_kernel(
    const u16* __restrict__ qb, const u16* __restrict__ kb,
    const u16* __restrict__ vT, float* __restrict__ out)
{
  const int bid  = blockIdx.x;
  const int h    = bid & 15;
  const int qt   = bid >> 4;          // 0..31
  const int tid  = threadIdx.x;
  const int w    = tid >> 6;
  const int lane = tid & 63;
  const int g    = lane >> 4;
  const int c    = lane & 15;
  const int sw   = qt * 64 + w * 16;

  __shared__ __align__(16) char kbuf[2][8192];   // [64 t][64 d] bf16 swizzled
  __shared__ __align__(16) char vbuf[2][8192];   // [64 e][64 t] bf16 swizzled

  const u16* kbh = kb + (size_t)h * SEQ * HD;
  const u16* vth = vT + (size_t)h * HD * SEQ;

  // Q B-frags for this wave's 16 rows (q pre-scaled by QSCALE in proj)
  bf16x8 qf[2];
#pragma unroll
  for (int ch = 0; ch < 2; ++ch)
    qf[ch] = as_frag(*(const uint4*)(
        qb + ((size_t)h * SEQ + sw + c) * HD + ch * 32 + g * 8));

  // hoisted LDS byte offsets (t-invariant)
  int qkoff[4][2];
#pragma unroll
  for (int tb = 0; tb < 4; ++tb)
#pragma unroll
    for (int ch = 0; ch < 2; ++ch)
      qkoff[tb][ch] = (tb * 16 + c) * 128 + ((((ch << 2) + g) ^ (c & 7)) << 4);
  int pvoff[4][2][2];
#pragma unroll
  for (int eb = 0; eb < 4; ++eb)
#pragma unroll
    for (int k0 = 0; k0 < 2; ++k0) {
      pvoff[eb][k0][0] = (eb * 16 + c) * 128 +
                         ((((k0 << 2) + 0 + (g >> 1)) ^ (c & 7)) << 4) + (g & 1) * 8;
      pvoff[eb][k0][1] = (eb * 16 + c) * 128 +
                         ((((k0 << 2) + 2 + (g >> 1)) ^ (c & 7)) << 4) + (g & 1) * 8;
    }

  // staging: thread covers 16B units u1,u2 of each 8KB tile (512 units)
  const int u1 = w * 128 + lane, u2 = u1 + 64;
  const int rr1 = u1 >> 3, sl1 = u1 & 7, rr2 = u2 >> 3, sl2 = u2 & 7;
  const char* gk1 = (const char*)kbh + rr1 * 128 + ((sl1 ^ (rr1 & 7)) << 4);
  const char* gk2 = (const char*)kbh + rr2 * 128 + ((sl2 ^ (rr2 & 7)) << 4);
  const char* gv1 = (const char*)vth + rr1 * 4096 + ((sl1 ^ (rr1 & 7)) << 4);
  const char* gv2 = (const char*)vth + rr2 * 4096 + ((sl2 ^ (rr2 & 7)) << 4);
  char* kd1 = (char*)kbuf + u1 * 16;
  char* kd2 = (char*)kbuf + u2 * 16;
  char* vd1 = (char*)vbuf + u1 * 16;
  char* vd2 = (char*)vbuf + u2 * 16;
  auto stage = [&](int buf) {
    int bo = buf * 8192;
    gload16(gk1, kd1 + bo);
    gload16(gk2, kd2 + bo);
    gload16(gv1, vd1 + bo);
    gload16(gv2, vd2 + bo);
    gk1 += 8192; gk2 += 8192; gv1 += 128; gv2 += 128;
  };

  f32x4 acc[4] = {};
  float m_ = -3e38f;
  float l_ = 0.f;

  stage(0);
  __syncthreads();

  for (int t = 0; t < 32; t += 2) {
#pragma unroll
    for (int tt = 0; tt < 2; ++tt) {
      if (t + tt + 1 < 32) stage(tt ^ 1);

      // QK^T (swapped): lane (g,c) holds S^T[tb*16+g*4+i][s = sw+c]
      f32x4 st_[4];
#pragma unroll
      for (int tb = 0; tb < 4; ++tb) {
        bf16x8 ka0 = as_frag(*(const uint4*)(kbuf[tt] + qkoff[tb][0]));
        bf16x8 ka1 = as_frag(*(const uint4*)(kbuf[tt] + qkoff[tb][1]));
        f32x4 z = {0.f, 0.f, 0.f, 0.f};
        z = mfma16(ka0, qf[0], z);
        st_[tb] = mfma16(ka1, qf[1], z);
      }

      // online softmax — R1's ops verbatim (exp2 domain, fresh max each tile)
      float mt = -3e38f;
#pragma unroll
      for (int tb = 0; tb < 4; ++tb)
#pragma unroll
        for (int i = 0; i < 4; ++i) mt = fmaxf(mt, st_[tb][i]);
      mt = fmaxf(mt, __shfl_xor(mt, 16));
      mt = fmaxf(mt, __shfl_xor(mt, 32));
      float mn = fmaxf(m_, mt);
      float al = exp2f(m_ - mn);        // first tile: exp2(-huge) = 0
      float p[4][4];
      float rs = 0.f;
#pragma unroll
      for (int tb = 0; tb < 4; ++tb)
#pragma unroll
        for (int i = 0; i < 4; ++i) {
          p[tb][i] = exp2f(st_[tb][i] - mn);
          rs += p[tb][i];
        }
      rs += __shfl_xor(rs, 16);
      rs += __shfl_xor(rs, 32);
      l_ = l_ * al + rs;
      m_ = mn;
#pragma unroll
      for (int eb = 0; eb < 4; ++eb) {
        acc[eb][0] *= al; acc[eb][1] *= al;
        acc[eb][2] *= al; acc[eb][3] *= al;
      }
      u32 pk[8];
#pragma unroll
      for (int tb = 0; tb < 4; ++tb) {
        pk[tb * 2 + 0] = pkbf(p[tb][0], p[tb][1]);
        pk[tb * 2 + 1] = pkbf(p[tb][2], p[tb][3]);
      }

      // PV: out^T += V^T @ P^T (B-frag = lane's own pk, zero shuffles)
#pragma unroll
      for (int eb = 0; eb < 4; ++eb) {
#pragma unroll
        for (int k0 = 0; k0 < 2; ++k0) {
          uint2 lo = *(const uint2*)(vbuf[tt] + pvoff[eb][k0][0]);
          uint2 hi = *(const uint2*)(vbuf[tt] + pvoff[eb][k0][1]);
          bf16x8 va = as_frag(make_uint4(lo.x, lo.y, hi.x, hi.y));
          bf16x8 pf = as_frag(make_uint4(pk[k0 * 4 + 0], pk[k0 * 4 + 1],
                                         pk[k0 * 4 + 2], pk[k0 * 4 + 3]));
          acc[eb] = mfma16(va, pf, acc[eb]);
        }
      }

      __syncthreads();   // drains stage (vmcnt0) + protects buffers
    }
  }

  // epilogue: lane (g,c) holds e = eb*16+g*4+i at s = sw+c
  const int s = sw + c;
  float rinv = 1.0f / l_;
#pragma unroll
  for (int eb = 0; eb < 4; ++eb) {
    float4 o;
    o.x = acc[eb][0] * rinv; o.y = acc[eb][1] * rinv;
    o.z = acc[eb][2] * rinv; o.w = acc[eb][3] * rinv;
    *(float4*)(out + (size_t)s * DIM + h * HD + eb * 16 + g * 4) = o;
  }
}

extern "C" void kernel_launch(void* const* d_in, const int* in_sizes, int n_in,
                              void* d_out, int out_size, void* d_ws, size_t ws_size,
                              hipStream_t stream) {
  const float* le = (const float*)d_in[0];
  const float* x  = le + (size_t)3 * SEQ * DIM;   // last batch image only
  const float* Wq = (const float*)d_in[1];
  const float* bq = (const float*)d_in[2];
  const float* Wk = (const float*)d_in[3];
  const float* bk = (const float*)d_in[4];
  const float* Wv = (const float*)d_in[5];
  const float* bv = (const float*)d_in[6];

  u16* qb = (u16*)d_ws;                               // 4 MB
  u16* kb = qb + (size_t)NH * SEQ * HD;               // 4 MB
  u16* vT = kb + (size_t)NH * SEQ * HD;               // 4 MB

  proj_kernel<<<512, 256, 0, stream>>>(x, Wq, bq, Wk, bk, Wv, bv, qb, kb, vT);
  attn_kernel<<<512, 256, 0, stream>>>(qb, kb, vT, (float*)d_out);
}